// Round 5
// baseline (126.780 us; speedup 1.0000x reference)
//
#include <hip/hip_runtime.h>
#include <math.h>

#define DIMS 3
#define NPTS 320
#define HID  128
#define RANK 64
#define ROWB 128   // bytes per f2 row = RANK * sizeof(bf16)
#define CQ   80    // c rows per block (quarter of NPTS)
#define NABT 1600  // a (320) x b-tiles (5)

typedef __attribute__((ext_vector_type(8))) short  bf16x8;
typedef __attribute__((ext_vector_type(4))) float  f32x4;

// round-to-nearest-even float -> bf16 bits
static __device__ __forceinline__ unsigned short f2bf_rn(float x) {
    union { float f; unsigned int u; } v; v.f = x;
    unsigned int r = v.u + 0x7fffu + ((v.u >> 16) & 1u);
    return (unsigned short)(r >> 16);
}
static __device__ __forceinline__ float bf2f(unsigned short h) {
    union { unsigned int u; float f; } v; v.u = ((unsigned int)h) << 16;
    return v.f;
}

// ---------------- Phase 1: per-dim MLP -> transposed factor tables ----------
__global__ __launch_bounds__(HID)
void mlp_kernel(const float* __restrict__ xs,
                const float* __restrict__ W0, const float* __restrict__ b0,
                const float* __restrict__ W1, const float* __restrict__ b1,
                const float* __restrict__ W2, const float* __restrict__ b2,
                const float* __restrict__ W3, const float* __restrict__ b3,
                float* __restrict__ f01t,
                unsigned short* __restrict__ f2hi,
                unsigned short* __restrict__ f2lo) {
    int blk = blockIdx.x;
    int d = blk / NPTS, n = blk % NPTS;
    int j = threadIdx.x;

    __shared__ float ha[HID];
    __shared__ float hb[HID];

    float x = xs[d * NPTS + n];

    ha[j] = tanhf(fmaf(x, W0[d * HID + j], b0[d * HID + j]));
    __syncthreads();

    {
        float acc = b1[d * HID + j];
        const float* w = W1 + d * HID * HID + j;
        #pragma unroll 16
        for (int k = 0; k < HID; ++k) acc = fmaf(ha[k], w[k * HID], acc);
        hb[j] = tanhf(acc);
    }
    __syncthreads();

    {
        float acc = b2[d * HID + j];
        const float* w = W2 + d * HID * HID + j;
        #pragma unroll 16
        for (int k = 0; k < HID; ++k) acc = fmaf(hb[k], w[k * HID], acc);
        ha[j] = tanhf(acc);
    }
    __syncthreads();

    if (j < RANK) {
        float acc = b3[d * RANK + j];
        const float* w = W3 + d * HID * RANK + j;
        #pragma unroll 16
        for (int k = 0; k < HID; ++k) acc = fmaf(ha[k], w[k * RANK], acc);

        if (d == 0) {
            f01t[n * RANK + j] = acc;                    // f0t[a][r]
        } else if (d == 1) {
            f01t[(NPTS + n) * RANK + j] = acc;           // f1t[b][r]
        } else {
            unsigned short hi = f2bf_rn(acc);
            f2hi[n * RANK + j] = hi;
            f2lo[n * RANK + j] = f2bf_rn(acc - bf2f(hi));
        }
    }
}

// ---------------- Phase 2: persistent-block CP reconstruction ----------------
// out[a,b,c] = sum_r (f0[a,r]*f1[b,r]) * f2[c,r]
// 2048 persistent blocks (8/CU, 32 waves/CU). Each block owns a c-quarter
// (80 rows, 20 KB LDS, swizzled) staged once; loops over (a, b-tile) pairs.
// ct-outer loop interleaves stores with MFMA compute (no store bursts).
__global__ __launch_bounds__(256, 8)
void cp_mfma_kernel(const float* __restrict__ f01t,
                    const unsigned short* __restrict__ f2hi,
                    const unsigned short* __restrict__ f2lo,
                    float* __restrict__ out) {
    const int tx = threadIdx.x;
    const int w  = tx >> 6;        // wave 0..3 -> b sub-tile
    const int l  = tx & 63;
    const int li = l & 15;         // B: row(c) / D: col(c)
    const int kg = l >> 4;         // k group 0..3

    const int cq = blockIdx.x & 3;
    const int c0 = cq * CQ;

    __shared__ char sB[2][CQ * ROWB];   // 20 KB, swizzled byte^=((row&7)<<4)

    // ---- stage this block's c-quarter of f2hi/f2lo (640 float4 each) ----
    #pragma unroll
    for (int i = 0; i < 3; ++i) {
        int idx = tx + i * 256;
        if (idx < CQ * 8) {
            int row   = idx >> 3;
            int inner = (idx & 7) << 4;
            int dst   = row * ROWB + (inner ^ ((row & 7) << 4));
            *(float4*)(&sB[0][dst]) = ((const float4*)f2hi)[c0 * 8 + idx];
            *(float4*)(&sB[1][dst]) = ((const float4*)f2lo)[c0 * 8 + idx];
        }
    }
    __syncthreads();

    for (int t = blockIdx.x >> 2; t < NABT; t += 512) {
        const int a  = t / 5;
        const int b0 = (t - a * 5) * 64;
        const float* f0p = f01t + (size_t)a * RANK;
        const float* f1p = f01t + (size_t)(NPTS + b0 + w * 16 + li) * RANK;

        // ---- build A fragments for both k-halves ----
        bf16x8 ahi[2], alo[2];
        #pragma unroll
        for (int ks = 0; ks < 2; ++ks) {
            const int k0 = ks * 32 + kg * 8;
            float4 f0a = *(const float4*)(f0p + k0);
            float4 f0b = *(const float4*)(f0p + k0 + 4);
            float4 f1a = *(const float4*)(f1p + k0);
            float4 f1b = *(const float4*)(f1p + k0 + 4);

            float g[8];
            g[0] = f1a.x * f0a.x; g[1] = f1a.y * f0a.y;
            g[2] = f1a.z * f0a.z; g[3] = f1a.w * f0a.w;
            g[4] = f1b.x * f0b.x; g[5] = f1b.y * f0b.y;
            g[6] = f1b.z * f0b.z; g[7] = f1b.w * f0b.w;

            #pragma unroll
            for (int j = 0; j < 8; ++j) {
                unsigned short hi = f2bf_rn(g[j]);
                ahi[ks][j] = (short)hi;
                alo[ks][j] = (short)f2bf_rn(g[j] - bf2f(hi));
            }
        }

        // ---- 5 c-tiles: 4 LDS reads + 6 MFMAs + 4 stores each ----
        float* obase = out + ((size_t)a * NPTS + (b0 + w * 16 + kg * 4)) * NPTS
                       + c0 + li;
        const int sw = (li & 7) << 4;
        #pragma unroll
        for (int ct = 0; ct < 5; ++ct) {
            const int rb = (ct * 16 + li) * ROWB;
            f32x4 acc = (f32x4){0.f, 0.f, 0.f, 0.f};
            #pragma unroll
            for (int ks = 0; ks < 2; ++ks) {
                const int boff = rb + ((ks * 64 + kg * 16) ^ sw);
                bf16x8 b_hi = *(const bf16x8*)(&sB[0][boff]);
                bf16x8 b_lo = *(const bf16x8*)(&sB[1][boff]);
                acc = __builtin_amdgcn_mfma_f32_16x16x32_bf16(ahi[ks], b_hi, acc, 0, 0, 0);
                acc = __builtin_amdgcn_mfma_f32_16x16x32_bf16(ahi[ks], b_lo, acc, 0, 0, 0);
                acc = __builtin_amdgcn_mfma_f32_16x16x32_bf16(alo[ks], b_hi, acc, 0, 0, 0);
            }
            // D layout: col(c)=li, row(b)=kg*4+q
            #pragma unroll
            for (int q = 0; q < 4; ++q)
                __builtin_nontemporal_store(acc[q], &obase[(size_t)q * NPTS + ct * 16]);
        }
    }
}

extern "C" void kernel_launch(void* const* d_in, const int* in_sizes, int n_in,
                              void* d_out, int out_size, void* d_ws, size_t ws_size,
                              hipStream_t stream) {
    const float* xs = (const float*)d_in[0];
    const float* W0 = (const float*)d_in[1];
    const float* b0 = (const float*)d_in[2];
    const float* W1 = (const float*)d_in[3];
    const float* b1 = (const float*)d_in[4];
    const float* W2 = (const float*)d_in[5];
    const float* b2 = (const float*)d_in[6];
    const float* W3 = (const float*)d_in[7];
    const float* b3 = (const float*)d_in[8];

    // workspace: f01t float[2][NPTS][RANK] | f2hi ushort[NPTS][RANK] | f2lo same
    float* f01t = (float*)d_ws;
    unsigned short* f2hi = (unsigned short*)((char*)d_ws + 2 * NPTS * RANK * 4);
    unsigned short* f2lo = f2hi + NPTS * RANK;
    float* out = (float*)d_out;

    mlp_kernel<<<dim3(DIMS * NPTS), dim3(HID), 0, stream>>>(
        xs, W0, b0, W1, b1, W2, b2, W3, b3, f01t, f2hi, f2lo);

    cp_mfma_kernel<<<dim3(2048), dim3(256), 0, stream>>>(f01t, f2hi, f2lo, out);
}

// Round 6
// 40.629 us; speedup vs baseline: 3.1204x; 3.1204x over previous
//
#include <hip/hip_runtime.h>
#include <math.h>

#define DIMS 3
#define NPTS 320
#define HID  128
#define RANK 64
#define CH   160   // c rows per block (half of NPTS)
#define LROW 256   // LDS bytes per c row: hi 128B | lo 128B, XOR-swizzled

typedef __attribute__((ext_vector_type(8)))  short bf16x8;
typedef __attribute__((ext_vector_type(16))) float f32x16;

// round-to-nearest-even float -> bf16 bits
static __device__ __forceinline__ unsigned short f2bf_rn(float x) {
    union { float f; unsigned int u; } v; v.f = x;
    unsigned int r = v.u + 0x7fffu + ((v.u >> 16) & 1u);
    return (unsigned short)(r >> 16);
}
static __device__ __forceinline__ float bf2f(unsigned short h) {
    union { unsigned int u; float f; } v; v.u = ((unsigned int)h) << 16;
    return v.f;
}

// ---------------- Phase 1: per-dim MLP -> transposed factor tables ----------
__global__ __launch_bounds__(HID)
void mlp_kernel(const float* __restrict__ xs,
                const float* __restrict__ W0, const float* __restrict__ b0,
                const float* __restrict__ W1, const float* __restrict__ b1,
                const float* __restrict__ W2, const float* __restrict__ b2,
                const float* __restrict__ W3, const float* __restrict__ b3,
                float* __restrict__ f01t,
                unsigned short* __restrict__ f2hi,
                unsigned short* __restrict__ f2lo) {
    int blk = blockIdx.x;
    int d = blk / NPTS, n = blk % NPTS;
    int j = threadIdx.x;

    __shared__ float ha[HID];
    __shared__ float hb[HID];

    float x = xs[d * NPTS + n];

    ha[j] = tanhf(fmaf(x, W0[d * HID + j], b0[d * HID + j]));
    __syncthreads();

    {
        float acc = b1[d * HID + j];
        const float* w = W1 + d * HID * HID + j;
        #pragma unroll 16
        for (int k = 0; k < HID; ++k) acc = fmaf(ha[k], w[k * HID], acc);
        hb[j] = tanhf(acc);
    }
    __syncthreads();

    {
        float acc = b2[d * HID + j];
        const float* w = W2 + d * HID * HID + j;
        #pragma unroll 16
        for (int k = 0; k < HID; ++k) acc = fmaf(hb[k], w[k * HID], acc);
        ha[j] = tanhf(acc);
    }
    __syncthreads();

    if (j < RANK) {
        float acc = b3[d * RANK + j];
        const float* w = W3 + d * HID * RANK + j;
        #pragma unroll 16
        for (int k = 0; k < HID; ++k) acc = fmaf(ha[k], w[k * RANK], acc);

        if (d == 0) {
            f01t[n * RANK + j] = acc;                    // f0t[a][r]
        } else if (d == 1) {
            f01t[(NPTS + n) * RANK + j] = acc;           // f1t[b][r]
        } else {
            unsigned short hi = f2bf_rn(acc);
            f2hi[n * RANK + j] = hi;
            f2lo[n * RANK + j] = f2bf_rn(acc - bf2f(hi));
        }
    }
}

// ---------------- Phase 2: persistent-block CP via 32x32x16 bf16 MFMA -------
// out[a,b,c] = sum_r (f0[a,r]*f1[b,r]) * f2[c,r]
// 1024 persistent blocks (4/CU), 128 threads = 2 waves. Block owns a c-half
// (160 rows staged once in 40 KB LDS, hi|lo interleaved 256B rows, XOR
// swizzle (row&15)<<4). Loop over (a, 64-b group); wave w takes b sub-tile
// w*32. D layout col=lane&31 => stores are full 128B lines.
__global__ __launch_bounds__(128, 2)
void cp_mfma_kernel(const float* __restrict__ f01t,
                    const unsigned short* __restrict__ f2hi,
                    const unsigned short* __restrict__ f2lo,
                    float* __restrict__ out) {
    const int tx = threadIdx.x;
    const int w  = tx >> 6;        // wave -> b sub-tile
    const int l  = tx & 63;
    const int lc = l & 31;         // A row(b) / B col(c) / D col(c)
    const int hw = l >> 5;         // half-wave -> k sub-group

    const int chalf = blockIdx.x & 1;
    const int c0 = chalf * CH;

    __shared__ char sB[CH * LROW];   // 40 KB

    // ---- stage c-half of f2hi/f2lo once (1280 float4 each) ----
    #pragma unroll
    for (int i = 0; i < 10; ++i) {
        int idx = tx + i * 128;               // 0..1279
        int row = idx >> 3;                   // local c row
        int g   = (idx & 7) << 4;             // byte granule within 128B
        int sw  = (row & 15) << 4;
        *(float4*)(&sB[row * LROW + (g ^ sw)]) =
            ((const float4*)f2hi)[c0 * 8 + idx];
        *(float4*)(&sB[row * LROW + ((128 + g) ^ sw)]) =
            ((const float4*)f2lo)[c0 * 8 + idx];
    }
    __syncthreads();

    for (int t = blockIdx.x >> 1; t < NPTS * 5; t += 512) {
        const int a    = t / 5;
        const int b0w  = (t - a * 5) * 64 + w * 32;
        const float* f0p = f01t + (size_t)a * RANK + hw * 8;
        const float* f1p = f01t + (size_t)(NPTS + b0w + lc) * RANK + hw * 8;

        // ---- A fragments: g[j] = f0[a][k]*f1[b][k], k = ks*16 + hw*8 + j ----
        bf16x8 ahi[4], alo[4];
        #pragma unroll
        for (int ks = 0; ks < 4; ++ks) {
            const int k0 = ks * 16;
            float4 f0a = *(const float4*)(f0p + k0);
            float4 f0b = *(const float4*)(f0p + k0 + 4);
            float4 f1a = *(const float4*)(f1p + k0);
            float4 f1b = *(const float4*)(f1p + k0 + 4);

            float g[8];
            g[0] = f1a.x * f0a.x; g[1] = f1a.y * f0a.y;
            g[2] = f1a.z * f0a.z; g[3] = f1a.w * f0a.w;
            g[4] = f1b.x * f0b.x; g[5] = f1b.y * f0b.y;
            g[6] = f1b.z * f0b.z; g[7] = f1b.w * f0b.w;

            #pragma unroll
            for (int j = 0; j < 8; ++j) {
                unsigned short hi = f2bf_rn(g[j]);
                ahi[ks][j] = (short)hi;
                alo[ks][j] = (short)f2bf_rn(g[j] - bf2f(hi));
            }
        }

        // ---- 5 c-tiles of 32: B from swizzled LDS, 12 MFMAs each ----
        #pragma unroll
        for (int ct = 0; ct < 5; ++ct) {
            const int lr = ct * 32 + lc;          // local c row for B
            const int sw = (lr & 15) << 4;
            const char* rowp = &sB[lr * LROW];

            f32x16 acc;
            #pragma unroll
            for (int j = 0; j < 16; ++j) acc[j] = 0.0f;

            #pragma unroll
            for (int ks = 0; ks < 4; ++ks) {
                const int base = ks * 32 + (hw << 4);        // byte offset in hi
                bf16x8 b_hi = *(const bf16x8*)(rowp + (base ^ sw));
                bf16x8 b_lo = *(const bf16x8*)(rowp + ((128 + base) ^ sw));
                acc = __builtin_amdgcn_mfma_f32_32x32x16_bf16(ahi[ks], b_hi, acc, 0, 0, 0);
                acc = __builtin_amdgcn_mfma_f32_32x32x16_bf16(ahi[ks], b_lo, acc, 0, 0, 0);
                acc = __builtin_amdgcn_mfma_f32_32x32x16_bf16(alo[ks], b_hi, acc, 0, 0, 0);
            }

            // D: col(c)=lc, row(b) = (q&3) + 8*(q>>2) + 4*hw
            float* obase = out + ((size_t)a * NPTS + b0w) * NPTS + c0 + ct * 32 + lc;
            #pragma unroll
            for (int q = 0; q < 16; ++q) {
                int row = (q & 3) + 8 * (q >> 2) + 4 * hw;
                obase[(size_t)row * NPTS] = acc[q];
            }
        }
    }
}

extern "C" void kernel_launch(void* const* d_in, const int* in_sizes, int n_in,
                              void* d_out, int out_size, void* d_ws, size_t ws_size,
                              hipStream_t stream) {
    const float* xs = (const float*)d_in[0];
    const float* W0 = (const float*)d_in[1];
    const float* b0 = (const float*)d_in[2];
    const float* W1 = (const float*)d_in[3];
    const float* b1 = (const float*)d_in[4];
    const float* W2 = (const float*)d_in[5];
    const float* b2 = (const float*)d_in[6];
    const float* W3 = (const float*)d_in[7];
    const float* b3 = (const float*)d_in[8];

    // workspace: f01t float[2][NPTS][RANK] | f2hi ushort[NPTS][RANK] | f2lo same
    float* f01t = (float*)d_ws;
    unsigned short* f2hi = (unsigned short*)((char*)d_ws + 2 * NPTS * RANK * 4);
    unsigned short* f2lo = f2hi + NPTS * RANK;
    float* out = (float*)d_out;

    mlp_kernel<<<dim3(DIMS * NPTS), dim3(HID), 0, stream>>>(
        xs, W0, b0, W1, b1, W2, b2, W3, b3, f01t, f2hi, f2lo);

    cp_mfma_kernel<<<dim3(1024), dim3(128), 0, stream>>>(f01t, f2hi, f2lo, out);
}